// Round 9
// baseline (412.472 us; speedup 1.0000x reference)
//
#include <hip/hip_runtime.h>

#define NEG_SLOPE 0.2f
#define SCAN_B 1024

typedef __attribute__((ext_vector_type(8))) short bf16x8;   // MFMA A/B frag
typedef __attribute__((ext_vector_type(4))) float f32x4;    // MFMA C/D frag

// fp32 -> bf16 round-to-nearest-even (no NaN inputs here).
__device__ __forceinline__ unsigned short f2b(float f) {
    unsigned int u = __float_as_uint(f);
    u += 0x7FFFu + ((u >> 16) & 1u);
    return (unsigned short)(u >> 16);
}
__device__ __forceinline__ float blo(unsigned int u) { return __uint_as_float(u << 16); }
__device__ __forceinline__ float bhi(unsigned int u) { return __uint_as_float(u & 0xFFFF0000u); }

// K1: h = bf16(x @ W1) [N,128]; asrc/adst from fp32 values. 2 nodes per block.
__global__ __launch_bounds__(256) void k_feat1(
    const float* __restrict__ x, const float* __restrict__ W1,
    const float* __restrict__ att_src, const float* __restrict__ att_dst,
    unsigned short* __restrict__ h, float* __restrict__ asrc,
    float* __restrict__ adst, int N)
{
    int n = blockIdx.x * 2 + (threadIdx.x >> 7);
    if (n >= N) return;
    int c = threadIdx.x & 127;          // flat channel = head*32+cc
    const float* xr = x + (size_t)n * 8;
    float acc = 0.f;
    #pragma unroll
    for (int k = 0; k < 8; k++) acc += xr[k] * W1[k * 128 + c];
    h[(size_t)n * 128 + c] = f2b(acc);
    float ps = acc * att_src[c];
    float pd = acc * att_dst[c];
    #pragma unroll
    for (int off = 16; off >= 1; off >>= 1) {
        ps += __shfl_xor(ps, off, 64);
        pd += __shfl_xor(pd, off, 64);
    }
    if ((c & 31) == 0) {
        int head = c >> 5;
        asrc[n * 4 + head] = ps;
        adst[n * 4 + head] = pd;
    }
}

// CSR step 1: histogram; returned old count IS the edge's within-bucket rank.
__global__ __launch_bounds__(256) void k_rank(
    const int* __restrict__ ei, int E, int EN,
    int* __restrict__ cnt, unsigned short* __restrict__ rank)
{
    int e = blockIdx.x * 256 + threadIdx.x;
    if (e >= EN) return;
    int dst = (e < E) ? ei[E + e] : (e - E);
    unsigned short r = (unsigned short)atomicAdd(&cnt[dst], 1);
    __builtin_nontemporal_store(r, rank + e);
}

// Scan phase A: per-1024-tile sums.
__global__ __launch_bounds__(SCAN_B) void k_scanA(
    const int* __restrict__ cnt, int* __restrict__ bsum, int N)
{
    __shared__ int red[SCAN_B];
    int t = threadIdx.x;
    int i = blockIdx.x * SCAN_B + t;
    red[t] = (i < N) ? cnt[i] : 0;
    __syncthreads();
    #pragma unroll
    for (int off = SCAN_B / 2; off > 0; off >>= 1) {
        if (t < off) red[t] += red[t + off];
        __syncthreads();
    }
    if (t == 0) bsum[blockIdx.x] = red[0];
}

// Scan phase B: exclusive scan of bsum[G] in one block (G <= 1024).
__global__ __launch_bounds__(SCAN_B) void k_scanB(int* __restrict__ bsum, int G)
{
    __shared__ int s[SCAN_B];
    int t = threadIdx.x;
    int v = (t < G) ? bsum[t] : 0;
    s[t] = v;
    __syncthreads();
    for (int off = 1; off < SCAN_B; off <<= 1) {
        int u = (t >= off) ? s[t - off] : 0;
        __syncthreads();
        s[t] += u;
        __syncthreads();
    }
    if (t < G) bsum[t] = s[t] - v;      // exclusive
}

// Scan phase C: intra-tile exclusive scan + block offset -> rowptr[N+1].
__global__ __launch_bounds__(SCAN_B) void k_scanC(
    const int* __restrict__ cnt, const int* __restrict__ bsum,
    int* __restrict__ rowptr, int N)
{
    __shared__ int s[SCAN_B];
    int t = threadIdx.x;
    int i = blockIdx.x * SCAN_B + t;
    int v = (i < N) ? cnt[i] : 0;
    s[t] = v;
    __syncthreads();
    for (int off = 1; off < SCAN_B; off <<= 1) {
        int u = (t >= off) ? s[t - off] : 0;
        __syncthreads();
        s[t] += u;
        __syncthreads();
    }
    int excl = s[t] - v + bsum[blockIdx.x];
    if (i < N) {
        rowptr[i] = excl;
        if (i == N - 1) rowptr[N] = excl + v;
    }
}

// CSR step 3: atomic-free placement using precomputed ranks.
__global__ __launch_bounds__(256) void k_place(
    const int* __restrict__ ei, int E, int EN,
    const int* __restrict__ rowptr, const unsigned short* __restrict__ rank,
    int* __restrict__ esrc)
{
    int e = blockIdx.x * 256 + threadIdx.x;
    if (e >= EN) return;
    int src, dst;
    if (e < E) { src = ei[e]; dst = ei[E + e]; }
    else       { src = dst = e - E; }
    esrc[rowptr[dst] + (int)rank[e]] = src;
}

// Aggregation core: 16 lanes per node (4 nodes per wave), 8 channels per lane.
// 8-wide edge batching: 8 independent gathers in flight to hide L2/L3 latency.
// Accumulation strictly in ascending-j order -> bitwise-stable vs any batching.
__device__ __forceinline__ void agg_edge(
    float w, uint4 u, float acc[8])
{
    acc[0] = fmaf(w, blo(u.x), acc[0]); acc[1] = fmaf(w, bhi(u.x), acc[1]);
    acc[2] = fmaf(w, blo(u.y), acc[2]); acc[3] = fmaf(w, bhi(u.y), acc[3]);
    acc[4] = fmaf(w, blo(u.z), acc[4]); acc[5] = fmaf(w, bhi(u.z), acc[5]);
    acc[6] = fmaf(w, blo(u.w), acc[6]); acc[7] = fmaf(w, bhi(u.w), acc[7]);
}

__device__ __forceinline__ void agg_core16(
    int n, int l4,
    const int* __restrict__ rowptr, const int* __restrict__ esrc,
    const uint4* __restrict__ h /* 16 uint4 per node */,
    const float* __restrict__ asrc, const float* __restrict__ adst,
    float acc[8], float& d)
{
    int head = l4 >> 2;
    float ad = adst[n * 4 + head];
    #pragma unroll
    for (int k = 0; k < 8; k++) acc[k] = 0.f;
    d = 0.f;
    int j = rowptr[n], end = rowptr[n + 1];

    for (; j + 8 <= end; j += 8) {
        int s[8]; float A[8]; uint4 u[8];
        #pragma unroll
        for (int k = 0; k < 8; k++) s[k] = __builtin_nontemporal_load(esrc + j + k);
        #pragma unroll
        for (int k = 0; k < 8; k++) A[k] = asrc[s[k] * 4 + head];
        #pragma unroll
        for (int k = 0; k < 8; k++) u[k] = h[(size_t)s[k] * 16 + l4];
        #pragma unroll
        for (int k = 0; k < 8; k++) {
            float a = A[k] + ad;
            a = a > 0.f ? a : NEG_SLOPE * a;
            float w = __expf(a);                // |a| small: no max-sub needed
            agg_edge(w, u[k], acc);
            d += w;
        }
    }
    if (j + 4 <= end) {
        int s[4]; float A[4]; uint4 u[4];
        #pragma unroll
        for (int k = 0; k < 4; k++) s[k] = __builtin_nontemporal_load(esrc + j + k);
        #pragma unroll
        for (int k = 0; k < 4; k++) A[k] = asrc[s[k] * 4 + head];
        #pragma unroll
        for (int k = 0; k < 4; k++) u[k] = h[(size_t)s[k] * 16 + l4];
        #pragma unroll
        for (int k = 0; k < 4; k++) {
            float a = A[k] + ad;
            a = a > 0.f ? a : NEG_SLOPE * a;
            float w = __expf(a);
            agg_edge(w, u[k], acc);
            d += w;
        }
        j += 4;
    }
    for (; j < end; j++) {
        int src = __builtin_nontemporal_load(esrc + j);
        float a = asrc[src * 4 + head] + ad;
        a = a > 0.f ? a : NEG_SLOPE * a;
        float w = __expf(a);
        uint4 u = h[(size_t)src * 16 + l4];
        agg_edge(w, u, acc);
        d += w;
    }
}

// Layer-1 aggregate + fused epilogue: out1 = bf16(relu(acc/denom + bias1)), packed.
__global__ __launch_bounds__(256) void k_agg1(
    const int* __restrict__ rowptr, const int* __restrict__ esrc,
    const uint4* __restrict__ h, const float* __restrict__ asrc,
    const float* __restrict__ adst, const float* __restrict__ bias,
    uint4* __restrict__ out1b, int N)
{
    int gid = blockIdx.x * 256 + threadIdx.x;
    int node = gid >> 4;
    if (node >= N) return;
    int l4 = threadIdx.x & 15;
    float acc[8], d;
    agg_core16(node, l4, rowptr, esrc, h, asrc, adst, acc, d);
    float inv = 1.f / d;
    const float4 b0 = *reinterpret_cast<const float4*>(bias + l4 * 8);
    const float4 b1 = *reinterpret_cast<const float4*>(bias + l4 * 8 + 4);
    float v[8];
    v[0] = acc[0] * inv + b0.x; v[1] = acc[1] * inv + b0.y;
    v[2] = acc[2] * inv + b0.z; v[3] = acc[3] * inv + b0.w;
    v[4] = acc[4] * inv + b1.x; v[5] = acc[5] * inv + b1.y;
    v[6] = acc[6] * inv + b1.z; v[7] = acc[7] * inv + b1.w;
    #pragma unroll
    for (int k = 0; k < 8; k++) v[k] = v[k] > 0.f ? v[k] : 0.f;
    uint4 o;
    o.x = ((unsigned int)f2b(v[1]) << 16) | f2b(v[0]);
    o.y = ((unsigned int)f2b(v[3]) << 16) | f2b(v[2]);
    o.z = ((unsigned int)f2b(v[5]) << 16) | f2b(v[4]);
    o.w = ((unsigned int)f2b(v[7]) << 16) | f2b(v[6]);
    out1b[(size_t)node * 16 + l4] = o;
}

// Layer-2 aggregate + fused final: mean over heads, +bias2, relu, dot W_lin.
__global__ __launch_bounds__(256) void k_agg2(
    const int* __restrict__ rowptr, const int* __restrict__ esrc,
    const uint4* __restrict__ h, const float* __restrict__ asrc,
    const float* __restrict__ adst, const float* __restrict__ bias2,
    const float* __restrict__ Wlin, const float* __restrict__ blin,
    float* __restrict__ out, int N)
{
    int gid = blockIdx.x * 256 + threadIdx.x;
    int node = gid >> 4;
    if (node >= N) return;
    int l4 = threadIdx.x & 15;
    float acc[8], d;
    agg_core16(node, l4, rowptr, esrc, h, asrc, adst, acc, d);
    float inv = 1.f / d;
    float v[8];
    #pragma unroll
    for (int k = 0; k < 8; k++) v[k] = acc[k] * inv;
    // head-mean: lanes differing in bits 2-3 of l4 hold same cc-octet, other heads
    #pragma unroll
    for (int k = 0; k < 8; k++) {
        v[k] += __shfl_xor(v[k], 4, 64);
        v[k] += __shfl_xor(v[k], 8, 64);
    }
    int cc = (l4 & 3) * 8;
    const float4 b0 = *reinterpret_cast<const float4*>(bias2 + cc);
    const float4 b1 = *reinterpret_cast<const float4*>(bias2 + cc + 4);
    const float4 w0 = *reinterpret_cast<const float4*>(Wlin + cc);
    const float4 w1 = *reinterpret_cast<const float4*>(Wlin + cc + 4);
    float bb[8] = {b0.x, b0.y, b0.z, b0.w, b1.x, b1.y, b1.z, b1.w};
    float ww[8] = {w0.x, w0.y, w0.z, w0.w, w1.x, w1.y, w1.z, w1.w};
    float t = 0.f;
    #pragma unroll
    for (int k = 0; k < 8; k++) {
        float m = 0.25f * v[k] + bb[k];
        float y = m > 0.f ? m : 0.f;
        t = fmaf(y, ww[k], t);
    }
    t += __shfl_xor(t, 1, 64);
    t += __shfl_xor(t, 2, 64);
    if (l4 == 0) out[node] = t + blin[0];
}

// Pack W2 (fp32 [128][128], k-major) into bf16 B-fragment layout.
__global__ __launch_bounds__(256) void k_packW2(
    const float* __restrict__ W2, unsigned short* __restrict__ W2p)
{
    int w = threadIdx.x >> 6, lane = threadIdx.x & 63;
    int quad = lane >> 4, lanelo = lane & 15;
    int tile_n = blockIdx.x;                    // 0..7
    size_t base = (((size_t)tile_n * 4 + w) * 64 + lane) * 8;
    #pragma unroll
    for (int j = 0; j < 8; j++) {
        int k = w * 32 + quad * 8 + j;
        int n = tile_n * 16 + lanelo;
        W2p[base + j] = f2b(W2[k * 128 + n]);
    }
}

// h2 = bf16(out1 @ W2) via MFMA + fused score computation.
// Block = 4 waves = 32 nodes x 128 cols; wave w covers cols [w*32, w*32+32) = head w.
__global__ __launch_bounds__(256) void k_feat2(
    const unsigned short* __restrict__ in_b,   // out1 bf16 [N][128]
    const unsigned short* __restrict__ W2p,    // packed B-fragments
    const float* __restrict__ att_src, const float* __restrict__ att_dst,
    unsigned short* __restrict__ h, float* __restrict__ asrc,
    float* __restrict__ adst, int N)
{
    int w = threadIdx.x >> 6;
    int lane = threadIdx.x & 63;
    int quad = lane >> 4, lanelo = lane & 15;
    int mbase = blockIdx.x * 32;
    int wcb = w * 32;                           // wave col base == head w * 32

    f32x4 acc[2][2];
    #pragma unroll
    for (int rt = 0; rt < 2; rt++)
        #pragma unroll
        for (int ct = 0; ct < 2; ct++)
            acc[rt][ct] = (f32x4){0.f, 0.f, 0.f, 0.f};

    #pragma unroll
    for (int kc = 0; kc < 4; kc++) {
        bf16x8 a[2], b[2];
        #pragma unroll
        for (int rt = 0; rt < 2; rt++) {
            int node = mbase + rt * 16 + lanelo;        // A: m = lane&15
            if (node >= N) node = N - 1;                // clamp (guard at store)
            a[rt] = *reinterpret_cast<const bf16x8*>(
                in_b + (size_t)node * 128 + kc * 32 + quad * 8);
        }
        #pragma unroll
        for (int ct = 0; ct < 2; ct++) {
            int tile_n = w * 2 + ct;
            b[ct] = *reinterpret_cast<const bf16x8*>(
                W2p + (((size_t)tile_n * 4 + kc) * 64 + lane) * 8);
        }
        #pragma unroll
        for (int rt = 0; rt < 2; rt++)
            #pragma unroll
            for (int ct = 0; ct < 2; ct++)
                acc[rt][ct] = __builtin_amdgcn_mfma_f32_16x16x32_bf16(
                    a[rt], b[ct], acc[rt][ct], 0, 0, 0);
    }

    // Epilogue. C/D layout: n = lane&15, m = quad*4 + reg.
    float as_[2], ad_[2];
    #pragma unroll
    for (int ct = 0; ct < 2; ct++) {
        int col = wcb + ct * 16 + lanelo;
        as_[ct] = att_src[col];
        ad_[ct] = att_dst[col];
    }
    #pragma unroll
    for (int rt = 0; rt < 2; rt++) {
        #pragma unroll
        for (int reg = 0; reg < 4; reg++) {
            int node = mbase + rt * 16 + quad * 4 + reg;
            bool ok = node < N;
            float v0 = acc[rt][0][reg], v1 = acc[rt][1][reg];
            if (ok) {
                h[(size_t)node * 128 + wcb + lanelo]      = f2b(v0);
                h[(size_t)node * 128 + wcb + 16 + lanelo] = f2b(v1);
            }
            float ps = v0 * as_[0] + v1 * as_[1];
            float pd = v0 * ad_[0] + v1 * ad_[1];
            #pragma unroll
            for (int off = 8; off >= 1; off >>= 1) {
                ps += __shfl_xor(ps, off, 64);
                pd += __shfl_xor(pd, off, 64);
            }
            if (ok && lanelo == 0) {
                asrc[node * 4 + w] = ps;
                adst[node * 4 + w] = pd;
            }
        }
    }
}

extern "C" void kernel_launch(void* const* d_in, const int* in_sizes, int n_in,
                              void* d_out, int out_size, void* d_ws, size_t ws_size,
                              hipStream_t stream)
{
    const float* x   = (const float*)d_in[0];
    const int*   ei  = (const int*)  d_in[1];
    const float* W1  = (const float*)d_in[2];
    const float* as1 = (const float*)d_in[3];
    const float* ad1 = (const float*)d_in[4];
    const float* b1  = (const float*)d_in[5];
    const float* W2  = (const float*)d_in[6];
    const float* as2 = (const float*)d_in[7];
    const float* ad2 = (const float*)d_in[8];
    const float* b2  = (const float*)d_in[9];
    const float* Wl  = (const float*)d_in[10];
    const float* bl  = (const float*)d_in[11];
    float* out = (float*)d_out;

    int N  = in_sizes[0] / 8;
    int E  = in_sizes[1] / 2;
    int EN = E + N;
    int G  = (N + SCAN_B - 1) / SCAN_B;

    float* ws    = (float*)d_ws;
    unsigned short* A = (unsigned short*)ws;    // N*128 bf16: h1, then h2
    float* B     = ws + (size_t)N * 64;         // region: rank, then out1 bf16
    float* asrc  = B + (size_t)N * 128;         // N*4
    float* adst  = asrc + (size_t)N * 4;        // N*4
    int* cnt     = (int*)(adst + (size_t)N * 4);// N
    int* rowptr  = cnt + N;                     // N+1
    int* bsum    = rowptr + N + 1;              // G
    int* esrc    = bsum + G;                    // EN
    unsigned short* W2p = (unsigned short*)(esrc + EN);  // 16384 bf16
    unsigned short* rank = (unsigned short*)B;  // EN u16, dead before k_agg1
    uint4* out1b = (uint4*)B;                   // N*16 uint4 (bf16x8)

    int eb = (EN + 255) / 256;
    int nb = (N + 15) / 16;                     // 16 nodes/block, 16 lanes/node

    // CSR build (shared by both layers) + W2 pack
    hipMemsetAsync(cnt, 0, (size_t)N * sizeof(int), stream);
    k_rank<<<eb, 256, 0, stream>>>(ei, E, EN, cnt, rank);
    k_scanA<<<G, SCAN_B, 0, stream>>>(cnt, bsum, N);
    k_scanB<<<1, SCAN_B, 0, stream>>>(bsum, G);
    k_scanC<<<G, SCAN_B, 0, stream>>>(cnt, bsum, rowptr, N);
    k_place<<<eb, 256, 0, stream>>>(ei, E, EN, rowptr, rank, esrc);
    k_packW2<<<8, 256, 0, stream>>>(W2, W2p);

    // Layer 1
    k_feat1<<<(N + 1) / 2, 256, 0, stream>>>(x, W1, as1, ad1, A, asrc, adst, N);
    k_agg1<<<nb, 256, 0, stream>>>(rowptr, esrc, (const uint4*)A,
                                   asrc, adst, b1, out1b, N);

    // Layer 2
    k_feat2<<<(N + 31) / 32, 256, 0, stream>>>((const unsigned short*)out1b, W2p,
                                               as2, ad2, A, asrc, adst, N);
    k_agg2<<<nb, 256, 0, stream>>>(rowptr, esrc, (const uint4*)A,
                                   asrc, adst, b2, Wl, bl, out, N);
}

// Round 10
// 361.374 us; speedup vs baseline: 1.1414x; 1.1414x over previous
//
#include <hip/hip_runtime.h>

#define NEG_SLOPE 0.2f
#define SCAN_B 1024

typedef __attribute__((ext_vector_type(8))) short bf16x8;   // MFMA A/B frag
typedef __attribute__((ext_vector_type(4))) float f32x4;    // MFMA C/D frag

// fp32 -> bf16 round-to-nearest-even (no NaN inputs here).
__device__ __forceinline__ unsigned short f2b(float f) {
    unsigned int u = __float_as_uint(f);
    u += 0x7FFFu + ((u >> 16) & 1u);
    return (unsigned short)(u >> 16);
}
__device__ __forceinline__ float blo(unsigned int u) { return __uint_as_float(u << 16); }
__device__ __forceinline__ float bhi(unsigned int u) { return __uint_as_float(u & 0xFFFF0000u); }

// Fold W1 with attention vectors: Wa[k][h] = sum_cc W1[k][h*32+cc]*att_src[h][cc].
__global__ void k_prep(const float* __restrict__ W1, const float* __restrict__ as1,
                       const float* __restrict__ ad1,
                       float* __restrict__ Wa, float* __restrict__ Wd)
{
    int t = threadIdx.x;
    if (t >= 32) return;
    int k = t >> 2, h = t & 3;
    float sa = 0.f, sd = 0.f;
    for (int cc = 0; cc < 32; cc++) {
        float w = W1[k * 128 + h * 32 + cc];
        sa = fmaf(w, as1[h * 32 + cc], sa);
        sd = fmaf(w, ad1[h * 32 + cc], sd);
    }
    Wa[k * 4 + h] = sa;
    Wd[k * 4 + h] = sd;
}

// Layer-1 scores straight from x: asrc[n,h] = x[n,:8] . Wa[:,h].
__global__ __launch_bounds__(256) void k_att1(
    const float* __restrict__ x, const float* __restrict__ Wa,
    const float* __restrict__ Wd, float* __restrict__ asrc,
    float* __restrict__ adst, int N)
{
    int t = blockIdx.x * 256 + threadIdx.x;
    int n = t >> 2;
    if (n >= N) return;
    int h = t & 3;
    const float* xr = x + (size_t)n * 8;
    float sa = 0.f, sd = 0.f;
    #pragma unroll
    for (int k = 0; k < 8; k++) {
        float xv = xr[k];
        sa = fmaf(xv, Wa[k * 4 + h], sa);
        sd = fmaf(xv, Wd[k * 4 + h], sd);
    }
    asrc[n * 4 + h] = sa;
    adst[n * 4 + h] = sd;
}

// CSR step 1: histogram; returned old count IS the edge's within-bucket rank.
__global__ __launch_bounds__(256) void k_rank(
    const int* __restrict__ ei, int E, int EN,
    int* __restrict__ cnt, unsigned short* __restrict__ rank)
{
    int e = blockIdx.x * 256 + threadIdx.x;
    if (e >= EN) return;
    int dst = (e < E) ? ei[E + e] : (e - E);
    unsigned short r = (unsigned short)atomicAdd(&cnt[dst], 1);
    __builtin_nontemporal_store(r, rank + e);
}

// Scan phase A: per-1024-tile sums.
__global__ __launch_bounds__(SCAN_B) void k_scanA(
    const int* __restrict__ cnt, int* __restrict__ bsum, int N)
{
    __shared__ int red[SCAN_B];
    int t = threadIdx.x;
    int i = blockIdx.x * SCAN_B + t;
    red[t] = (i < N) ? cnt[i] : 0;
    __syncthreads();
    #pragma unroll
    for (int off = SCAN_B / 2; off > 0; off >>= 1) {
        if (t < off) red[t] += red[t + off];
        __syncthreads();
    }
    if (t == 0) bsum[blockIdx.x] = red[0];
}

// Scan phase B: exclusive scan of bsum[G] in one block (G <= 1024).
__global__ __launch_bounds__(SCAN_B) void k_scanB(int* __restrict__ bsum, int G)
{
    __shared__ int s[SCAN_B];
    int t = threadIdx.x;
    int v = (t < G) ? bsum[t] : 0;
    s[t] = v;
    __syncthreads();
    for (int off = 1; off < SCAN_B; off <<= 1) {
        int u = (t >= off) ? s[t - off] : 0;
        __syncthreads();
        s[t] += u;
        __syncthreads();
    }
    if (t < G) bsum[t] = s[t] - v;      // exclusive
}

// Scan phase C: intra-tile exclusive scan + block offset -> rowptr[N+1].
__global__ __launch_bounds__(SCAN_B) void k_scanC(
    const int* __restrict__ cnt, const int* __restrict__ bsum,
    int* __restrict__ rowptr, int N)
{
    __shared__ int s[SCAN_B];
    int t = threadIdx.x;
    int i = blockIdx.x * SCAN_B + t;
    int v = (i < N) ? cnt[i] : 0;
    s[t] = v;
    __syncthreads();
    for (int off = 1; off < SCAN_B; off <<= 1) {
        int u = (t >= off) ? s[t - off] : 0;
        __syncthreads();
        s[t] += u;
        __syncthreads();
    }
    int excl = s[t] - v + bsum[blockIdx.x];
    if (i < N) {
        rowptr[i] = excl;
        if (i == N - 1) rowptr[N] = excl + v;
    }
}

// CSR step 3: atomic-free placement using precomputed ranks.
__global__ __launch_bounds__(256) void k_place(
    const int* __restrict__ ei, int E, int EN,
    const int* __restrict__ rowptr, const unsigned short* __restrict__ rank,
    int* __restrict__ esrc)
{
    int e = blockIdx.x * 256 + threadIdx.x;
    if (e >= EN) return;
    int src, dst;
    if (e < E) { src = ei[e]; dst = ei[E + e]; }
    else       { src = dst = e - E; }
    esrc[rowptr[dst] + (int)rank[e]] = src;
}

// Layer-1 aggregation in INPUT space (x is 8-dim, L2-resident):
// y[dst,h,:] = sum_e w_eh * x[src_e,:]. 8 lanes/node: lane = head*2 + dim-half.
__global__ __launch_bounds__(256) void k_aggx(
    const int* __restrict__ rowptr, const int* __restrict__ esrc,
    const float* __restrict__ x, const float* __restrict__ asrc,
    const float* __restrict__ adst,
    float* __restrict__ y, float* __restrict__ denom, int N)
{
    int gid = blockIdx.x * 256 + threadIdx.x;
    int node = gid >> 3;
    if (node >= N) return;
    int l8 = threadIdx.x & 7;
    int h = l8 >> 1;
    int dh = (l8 & 1) << 2;
    float ad = adst[node * 4 + h];
    float a0 = 0.f, a1 = 0.f, a2 = 0.f, a3 = 0.f, d = 0.f;
    int j = rowptr[node], end = rowptr[node + 1];
    for (; j + 4 <= end; j += 4) {
        int s0 = esrc[j], s1 = esrc[j + 1], s2 = esrc[j + 2], s3 = esrc[j + 3];
        float A0 = asrc[s0 * 4 + h];
        float A1 = asrc[s1 * 4 + h];
        float A2 = asrc[s2 * 4 + h];
        float A3 = asrc[s3 * 4 + h];
        float4 x0 = *reinterpret_cast<const float4*>(x + (size_t)s0 * 8 + dh);
        float4 x1 = *reinterpret_cast<const float4*>(x + (size_t)s1 * 8 + dh);
        float4 x2 = *reinterpret_cast<const float4*>(x + (size_t)s2 * 8 + dh);
        float4 x3 = *reinterpret_cast<const float4*>(x + (size_t)s3 * 8 + dh);
        A0 += ad; A0 = A0 > 0.f ? A0 : NEG_SLOPE * A0; float w0 = __expf(A0);
        A1 += ad; A1 = A1 > 0.f ? A1 : NEG_SLOPE * A1; float w1 = __expf(A1);
        A2 += ad; A2 = A2 > 0.f ? A2 : NEG_SLOPE * A2; float w2 = __expf(A2);
        A3 += ad; A3 = A3 > 0.f ? A3 : NEG_SLOPE * A3; float w3 = __expf(A3);
        a0 = fmaf(w0, x0.x, a0); a1 = fmaf(w0, x0.y, a1);
        a2 = fmaf(w0, x0.z, a2); a3 = fmaf(w0, x0.w, a3); d += w0;
        a0 = fmaf(w1, x1.x, a0); a1 = fmaf(w1, x1.y, a1);
        a2 = fmaf(w1, x1.z, a2); a3 = fmaf(w1, x1.w, a3); d += w1;
        a0 = fmaf(w2, x2.x, a0); a1 = fmaf(w2, x2.y, a1);
        a2 = fmaf(w2, x2.z, a2); a3 = fmaf(w2, x2.w, a3); d += w2;
        a0 = fmaf(w3, x3.x, a0); a1 = fmaf(w3, x3.y, a1);
        a2 = fmaf(w3, x3.z, a2); a3 = fmaf(w3, x3.w, a3); d += w3;
    }
    for (; j < end; j++) {
        int src = esrc[j];
        float a = asrc[src * 4 + h] + ad;
        a = a > 0.f ? a : NEG_SLOPE * a;
        float w = __expf(a);
        float4 xv = *reinterpret_cast<const float4*>(x + (size_t)src * 8 + dh);
        a0 = fmaf(w, xv.x, a0); a1 = fmaf(w, xv.y, a1);
        a2 = fmaf(w, xv.z, a2); a3 = fmaf(w, xv.w, a3); d += w;
    }
    float4 o = {a0, a1, a2, a3};
    *reinterpret_cast<float4*>(y + ((size_t)node * 4 + h) * 8 + dh) = o;
    if (dh == 0) denom[node * 4 + h] = d;
}

// out1 = bf16(relu((y @ W1)/denom + bias1)), packed. 64 lanes/node, 2 ch/lane.
__global__ __launch_bounds__(256) void k_out1(
    const float* __restrict__ y, const float* __restrict__ denom,
    const float* __restrict__ W1, const float* __restrict__ bias,
    unsigned int* __restrict__ out1b, int N)
{
    int node = blockIdx.x * 4 + (threadIdx.x >> 6);
    if (node >= N) return;
    int lane = threadIdx.x & 63;
    int h = lane >> 4;                      // c0 = 2*lane, head = c0>>5
    float inv = 1.f / denom[node * 4 + h];
    const float* yr = y + ((size_t)node * 4 + h) * 8;
    float y8[8];
    #pragma unroll
    for (int k = 0; k < 8; k++) y8[k] = yr[k];
    int c0 = 2 * lane;
    float v0 = 0.f, v1 = 0.f;
    #pragma unroll
    for (int k = 0; k < 8; k++) {
        float2 wv = *reinterpret_cast<const float2*>(W1 + k * 128 + c0);
        v0 = fmaf(y8[k], wv.x, v0);
        v1 = fmaf(y8[k], wv.y, v1);
    }
    const float2 bv = *reinterpret_cast<const float2*>(bias + c0);
    v0 = v0 * inv + bv.x;
    v1 = v1 * inv + bv.y;
    v0 = v0 > 0.f ? v0 : 0.f;
    v1 = v1 > 0.f ? v1 : 0.f;
    out1b[(size_t)node * 64 + lane] = ((unsigned int)f2b(v1) << 16) | f2b(v0);
}

// Layer-2 aggregation core (r8 version): 16 lanes/node, 8 ch/lane, 4-wide batch.
__device__ __forceinline__ void agg_edge(float w, uint4 u, float acc[8])
{
    acc[0] = fmaf(w, blo(u.x), acc[0]); acc[1] = fmaf(w, bhi(u.x), acc[1]);
    acc[2] = fmaf(w, blo(u.y), acc[2]); acc[3] = fmaf(w, bhi(u.y), acc[3]);
    acc[4] = fmaf(w, blo(u.z), acc[4]); acc[5] = fmaf(w, bhi(u.z), acc[5]);
    acc[6] = fmaf(w, blo(u.w), acc[6]); acc[7] = fmaf(w, bhi(u.w), acc[7]);
}

__device__ __forceinline__ void agg_core16(
    int n, int l4,
    const int* __restrict__ rowptr, const int* __restrict__ esrc,
    const uint4* __restrict__ h /* 16 uint4 per node */,
    const float* __restrict__ asrc, const float* __restrict__ adst,
    float acc[8], float& d)
{
    int head = l4 >> 2;
    float ad = adst[n * 4 + head];
    #pragma unroll
    for (int k = 0; k < 8; k++) acc[k] = 0.f;
    d = 0.f;
    int j = rowptr[n], end = rowptr[n + 1];

    for (; j + 4 <= end; j += 4) {
        int s0 = esrc[j], s1 = esrc[j + 1], s2 = esrc[j + 2], s3 = esrc[j + 3];
        float A0 = asrc[s0 * 4 + head];
        float A1 = asrc[s1 * 4 + head];
        float A2 = asrc[s2 * 4 + head];
        float A3 = asrc[s3 * 4 + head];
        uint4 u0 = h[(size_t)s0 * 16 + l4];
        uint4 u1 = h[(size_t)s1 * 16 + l4];
        uint4 u2 = h[(size_t)s2 * 16 + l4];
        uint4 u3 = h[(size_t)s3 * 16 + l4];
        A0 += ad; A0 = A0 > 0.f ? A0 : NEG_SLOPE * A0; float w0 = __expf(A0);
        A1 += ad; A1 = A1 > 0.f ? A1 : NEG_SLOPE * A1; float w1 = __expf(A1);
        A2 += ad; A2 = A2 > 0.f ? A2 : NEG_SLOPE * A2; float w2 = __expf(A2);
        A3 += ad; A3 = A3 > 0.f ? A3 : NEG_SLOPE * A3; float w3 = __expf(A3);
        agg_edge(w0, u0, acc); d += w0;
        agg_edge(w1, u1, acc); d += w1;
        agg_edge(w2, u2, acc); d += w2;
        agg_edge(w3, u3, acc); d += w3;
    }
    for (; j < end; j++) {
        int src = esrc[j];
        float a = asrc[src * 4 + head] + ad;
        a = a > 0.f ? a : NEG_SLOPE * a;
        float w = __expf(a);
        uint4 u = h[(size_t)src * 16 + l4];
        agg_edge(w, u, acc); d += w;
    }
}

// Layer-2 aggregate + fused final: mean over heads, +bias2, relu, dot W_lin.
__global__ __launch_bounds__(256) void k_agg2(
    const int* __restrict__ rowptr, const int* __restrict__ esrc,
    const uint4* __restrict__ h, const float* __restrict__ asrc,
    const float* __restrict__ adst, const float* __restrict__ bias2,
    const float* __restrict__ Wlin, const float* __restrict__ blin,
    float* __restrict__ out, int N)
{
    int gid = blockIdx.x * 256 + threadIdx.x;
    int node = gid >> 4;
    if (node >= N) return;
    int l4 = threadIdx.x & 15;
    float acc[8], d;
    agg_core16(node, l4, rowptr, esrc, h, asrc, adst, acc, d);
    float inv = 1.f / d;
    float v[8];
    #pragma unroll
    for (int k = 0; k < 8; k++) v[k] = acc[k] * inv;
    // head-mean: lanes differing in bits 2-3 of l4 hold same cc-octet, other heads
    #pragma unroll
    for (int k = 0; k < 8; k++) {
        v[k] += __shfl_xor(v[k], 4, 64);
        v[k] += __shfl_xor(v[k], 8, 64);
    }
    int cc = (l4 & 3) * 8;
    const float4 b0 = *reinterpret_cast<const float4*>(bias2 + cc);
    const float4 b1 = *reinterpret_cast<const float4*>(bias2 + cc + 4);
    const float4 w0 = *reinterpret_cast<const float4*>(Wlin + cc);
    const float4 w1 = *reinterpret_cast<const float4*>(Wlin + cc + 4);
    float bb[8] = {b0.x, b0.y, b0.z, b0.w, b1.x, b1.y, b1.z, b1.w};
    float ww[8] = {w0.x, w0.y, w0.z, w0.w, w1.x, w1.y, w1.z, w1.w};
    float t = 0.f;
    #pragma unroll
    for (int k = 0; k < 8; k++) {
        float m = 0.25f * v[k] + bb[k];
        float y = m > 0.f ? m : 0.f;
        t = fmaf(y, ww[k], t);
    }
    t += __shfl_xor(t, 1, 64);
    t += __shfl_xor(t, 2, 64);
    if (l4 == 0) out[node] = t + blin[0];
}

// Pack W2 (fp32 [128][128], k-major) into bf16 B-fragment layout.
__global__ __launch_bounds__(256) void k_packW2(
    const float* __restrict__ W2, unsigned short* __restrict__ W2p)
{
    int w = threadIdx.x >> 6, lane = threadIdx.x & 63;
    int quad = lane >> 4, lanelo = lane & 15;
    int tile_n = blockIdx.x;                    // 0..7
    size_t base = (((size_t)tile_n * 4 + w) * 64 + lane) * 8;
    #pragma unroll
    for (int j = 0; j < 8; j++) {
        int k = w * 32 + quad * 8 + j;
        int n = tile_n * 16 + lanelo;
        W2p[base + j] = f2b(W2[k * 128 + n]);
    }
}

// h2 = bf16(out1 @ W2) via MFMA + fused score computation.
// Block = 4 waves = 32 nodes x 128 cols; wave w covers cols [w*32, w*32+32) = head w.
__global__ __launch_bounds__(256) void k_feat2(
    const unsigned short* __restrict__ in_b,   // out1 bf16 [N][128]
    const unsigned short* __restrict__ W2p,    // packed B-fragments
    const float* __restrict__ att_src, const float* __restrict__ att_dst,
    unsigned short* __restrict__ h, float* __restrict__ asrc,
    float* __restrict__ adst, int N)
{
    int w = threadIdx.x >> 6;
    int lane = threadIdx.x & 63;
    int quad = lane >> 4, lanelo = lane & 15;
    int mbase = blockIdx.x * 32;
    int wcb = w * 32;                           // wave col base == head w * 32

    f32x4 acc[2][2];
    #pragma unroll
    for (int rt = 0; rt < 2; rt++)
        #pragma unroll
        for (int ct = 0; ct < 2; ct++)
            acc[rt][ct] = (f32x4){0.f, 0.f, 0.f, 0.f};

    #pragma unroll
    for (int kc = 0; kc < 4; kc++) {
        bf16x8 a[2], b[2];
        #pragma unroll
        for (int rt = 0; rt < 2; rt++) {
            int node = mbase + rt * 16 + lanelo;        // A: m = lane&15
            if (node >= N) node = N - 1;                // clamp (guard at store)
            a[rt] = *reinterpret_cast<const bf16x8*>(
                in_b + (size_t)node * 128 + kc * 32 + quad * 8);
        }
        #pragma unroll
        for (int ct = 0; ct < 2; ct++) {
            int tile_n = w * 2 + ct;
            b[ct] = *reinterpret_cast<const bf16x8*>(
                W2p + (((size_t)tile_n * 4 + kc) * 64 + lane) * 8);
        }
        #pragma unroll
        for (int rt = 0; rt < 2; rt++)
            #pragma unroll
            for (int ct = 0; ct < 2; ct++)
                acc[rt][ct] = __builtin_amdgcn_mfma_f32_16x16x32_bf16(
                    a[rt], b[ct], acc[rt][ct], 0, 0, 0);
    }

    // Epilogue. C/D layout: n = lane&15, m = quad*4 + reg.
    float as_[2], ad_[2];
    #pragma unroll
    for (int ct = 0; ct < 2; ct++) {
        int col = wcb + ct * 16 + lanelo;
        as_[ct] = att_src[col];
        ad_[ct] = att_dst[col];
    }
    #pragma unroll
    for (int rt = 0; rt < 2; rt++) {
        #pragma unroll
        for (int reg = 0; reg < 4; reg++) {
            int node = mbase + rt * 16 + quad * 4 + reg;
            bool ok = node < N;
            float v0 = acc[rt][0][reg], v1 = acc[rt][1][reg];
            if (ok) {
                h[(size_t)node * 128 + wcb + lanelo]      = f2b(v0);
                h[(size_t)node * 128 + wcb + 16 + lanelo] = f2b(v1);
            }
            float ps = v0 * as_[0] + v1 * as_[1];
            float pd = v0 * ad_[0] + v1 * ad_[1];
            #pragma unroll
            for (int off = 8; off >= 1; off >>= 1) {
                ps += __shfl_xor(ps, off, 64);
                pd += __shfl_xor(pd, off, 64);
            }
            if (ok && lanelo == 0) {
                asrc[node * 4 + w] = ps;
                adst[node * 4 + w] = pd;
            }
        }
    }
}

extern "C" void kernel_launch(void* const* d_in, const int* in_sizes, int n_in,
                              void* d_out, int out_size, void* d_ws, size_t ws_size,
                              hipStream_t stream)
{
    const float* x   = (const float*)d_in[0];
    const int*   ei  = (const int*)  d_in[1];
    const float* W1  = (const float*)d_in[2];
    const float* as1 = (const float*)d_in[3];
    const float* ad1 = (const float*)d_in[4];
    const float* b1  = (const float*)d_in[5];
    const float* W2  = (const float*)d_in[6];
    const float* as2 = (const float*)d_in[7];
    const float* ad2 = (const float*)d_in[8];
    const float* b2  = (const float*)d_in[9];
    const float* Wl  = (const float*)d_in[10];
    const float* bl  = (const float*)d_in[11];
    float* out = (float*)d_out;

    int N  = in_sizes[0] / 8;
    int E  = in_sizes[1] / 2;
    int EN = E + N;
    int G  = (N + SCAN_B - 1) / SCAN_B;

    float* ws    = (float*)d_ws;
    unsigned short* A = (unsigned short*)ws;    // N*128 bf16: h2; y aliases this
    float* y     = ws;                          // N*32 fp32 (layer-1 aggregate)
    float* B     = ws + (size_t)N * 64;         // region: rank, then out1 bf16
    float* asrc  = B + (size_t)N * 128;         // N*4
    float* adst  = asrc + (size_t)N * 4;        // N*4
    int* cnt     = (int*)(adst + (size_t)N * 4);// N
    int* rowptr  = cnt + N;                     // N+1
    int* bsum    = rowptr + N + 1;              // G
    int* esrc    = bsum + G;                    // EN
    unsigned short* W2p = (unsigned short*)(esrc + EN);  // 16384 bf16
    float* Wa    = (float*)(W2p + 16384);       // 32
    float* Wd    = Wa + 32;                     // 32
    float* denom = Wd + 32;                     // N*4
    unsigned short* rank = (unsigned short*)B;  // EN u16, dead before k_out1
    unsigned int* out1b = (unsigned int*)B;     // N*64 dwords (bf16x8)

    int eb = (EN + 255) / 256;
    int nb = (N + 15) / 16;                     // agg2: 16 nodes/block

    // CSR build (shared by both layers) + weight prep
    hipMemsetAsync(cnt, 0, (size_t)N * sizeof(int), stream);
    k_rank<<<eb, 256, 0, stream>>>(ei, E, EN, cnt, rank);
    k_scanA<<<G, SCAN_B, 0, stream>>>(cnt, bsum, N);
    k_scanB<<<1, SCAN_B, 0, stream>>>(bsum, G);
    k_scanC<<<G, SCAN_B, 0, stream>>>(cnt, bsum, rowptr, N);
    k_place<<<eb, 256, 0, stream>>>(ei, E, EN, rowptr, rank, esrc);
    k_packW2<<<8, 256, 0, stream>>>(W2, W2p);
    k_prep<<<1, 64, 0, stream>>>(W1, as1, ad1, Wa, Wd);

    // Layer 1 (input-space aggregation: no h1 materialization)
    k_att1<<<(N + 63) / 64, 256, 0, stream>>>(x, Wa, Wd, asrc, adst, N);
    k_aggx<<<(N + 31) / 32, 256, 0, stream>>>(rowptr, esrc, x, asrc, adst,
                                              y, denom, N);
    k_out1<<<(N + 3) / 4, 256, 0, stream>>>(y, denom, W1, b1, out1b, N);

    // Layer 2
    k_feat2<<<(N + 31) / 32, 256, 0, stream>>>((const unsigned short*)out1b, W2p,
                                               as2, ad2, A, asrc, adst, N);
    k_agg2<<<nb, 256, 0, stream>>>(rowptr, esrc, (const uint4*)A,
                                   asrc, adst, b2, Wl, bl, out, N);
}